// Round 8
// baseline (412.225 us; speedup 1.0000x reference)
//
#include <hip/hip_runtime.h>
#include <hip/hip_bf16.h>
#include <math.h>

#define S_ 4
#define N_ 4096
#define M_ 4096
#define D_ 128
#define NEG_ (-1e30f)
#define CH_ 2              // m-chunks per stem
#define MCH_ (M_ / CH_)    // 2048 m per chunk
#define NST_ (MCH_ / 64)   // 32 stages of 64 m
#define LN2_ 0.69314718055994531f
#define LOG2E_ 1.44269504088896340f

typedef __bf16 bf16x8 __attribute__((ext_vector_type(8)));
typedef float f32x4 __attribute__((ext_vector_type(4)));

// async global->LDS, 16B per lane (dest = wave-uniform base + lane*16)
__device__ __forceinline__ void gll16(const void* g, void* l) {
    __builtin_amdgcn_global_load_lds(
        (const __attribute__((address_space(1))) unsigned int*)g,
        (__attribute__((address_space(3))) unsigned int*)l, 16, 0, 0);
}

// RNE float -> bf16 bits
__device__ __forceinline__ unsigned short f2bf(float f) {
    unsigned u = __float_as_uint(f);
    unsigned r = (u + 0x7FFFu + ((u >> 16) & 1u)) >> 16;
    return (unsigned short)r;
}

// ---------------- Phase 1: L2-normalize art AND ref rows, write bf16 ----------------
// wave handles 2 rows; lane covers 4 elements (float4). 4096 blocks.
__global__ void nrm_rows_kernel(const float* __restrict__ art, const float* __restrict__ ref,
                                unsigned short* __restrict__ an, unsigned short* __restrict__ rn) {
    const int w = threadIdx.x >> 6;
    const int lane = threadIdx.x & 63;
    const int half = lane >> 5;
    const int li = lane & 31;
    const int row = blockIdx.x * 8 + w * 2 + half;   // 0 .. S_*(N_+M_)-1
    const bool is_art = row < S_ * N_;
    const float* src = is_art ? (art + (size_t)row * D_)
                              : (ref + (size_t)(row - S_ * N_) * D_);
    unsigned short* dst = is_art ? (an + (size_t)row * D_)
                                 : (rn + (size_t)(row - S_ * N_) * D_);
    const float4 v = *reinterpret_cast<const float4*>(src + li * 4);
    float ss = v.x * v.x + v.y * v.y + v.z * v.z + v.w * v.w;
#pragma unroll
    for (int off = 1; off < 32; off <<= 1) ss += __shfl_xor(ss, off);
    const float scale = 1.0f / fmaxf(sqrtf(ss), 1e-12f);
    uint2 pack;
    pack.x = (unsigned)f2bf(v.x * scale) | ((unsigned)f2bf(v.y * scale) << 16);
    pack.y = (unsigned)f2bf(v.z * scale) | ((unsigned)f2bf(v.w * scale) << 16);
    *reinterpret_cast<uint2*>(dst + li * 4) = pack;
}

// ---------------- Phase 2: LDS-staged GEMM + fused mask stream + online LSE ----------------
// 1024 blocks (CH_ x S_ x 128 n-blocks) x 4 waves, 4 blocks/CU = one generation.
// Counted-vmcnt stage barriers (T3/T4): per stage issue [4x global_load_lds (rn st+1)]
// [sched_barrier] [8x mask byte loads (st+2)], then MFMA + epilogue + ballot(st+1),
// then s_waitcnt vmcnt(8) + raw s_barrier -> the 8 HBM mask loads stay in flight
// across the barrier; only the L2 rn DMAs are drained.
__global__ __launch_bounds__(256, 4) void infonce_main_kernel(
    const unsigned short* __restrict__ an, const unsigned short* __restrict__ rn,
    const unsigned char* __restrict__ maskb, const float* __restrict__ logtemp,
    float4* __restrict__ part4) {

    const int bid = blockIdx.x;
    const int swz = (bid & 7) * 128 + (bid >> 3);   // 1024 % 8 == 0 -> bijective
    const int ch = swz >> 9;                        // 0..1
    const int s = (swz >> 7) & 3;                   // 0..3
    const int nblk = swz & 127;                     // 0..127
    const int n_base = nblk * 32;

    const int tid = threadIdx.x;
    const int w = tid >> 6;
    const int lane = tid & 63;
    const int nsub = w & 1;
    const int msub = w >> 1;
    const int n16 = n_base + nsub * 16;
    const int lrow = lane & 15;        // anchor col within 16-group
    const int lgrp = lane >> 4;        // k-group / m-row group
    const float scale2 = __expf(-logtemp[0]) * LOG2E_;   // 1/(temp*ln2)

    // mask dtype detection over 1 KB: byte-packed bools seen as u32 show values > 1
    const unsigned* mu = (const unsigned*)maskb;
    unsigned pr = 0;
#pragma unroll
    for (int i = 0; i < 4; ++i) pr |= (mu[i * 64 + lane] > 1u) ? 1u : 0u;
    const bool byte_mode = (__ballot(pr != 0) != 0ull);
    const size_t mstride = byte_mode ? 1 : 4;

    __shared__ unsigned char smem[2][64 * 256];     // 2 x 16 KB rn stage buffers
    __shared__ unsigned long long mbuf[2][32];      // 2 x 32 row-bitwords
    __shared__ float4 lds4[4][16];

    // anchor fragments resident in registers
    bf16x8 bfr[4];
    const unsigned short* abase = an + ((size_t)(s * N_ + n16 + lrow)) * D_ + lgrp * 8;
#pragma unroll
    for (int kc = 0; kc < 4; ++kc)
        bfr[kc] = *reinterpret_cast<const bf16x8*>(abase + kc * 32);

    // rn staging: thread covers row srow (+j*16), 16B chunk (lane&15), source XOR-swizzled
    const int srow = w * 4 + (lane >> 4);           // 0..15
    const int schunk = (lane & 15) ^ (srow & 7);
    const int lane_src_off = srow * 256 + schunk * 16;
    const unsigned char* rn_chunk =
        (const unsigned char*)(rn + ((size_t)(s * M_ + ch * MCH_)) * D_);

    // mask row byte-bases for this wave's 8 rows (block anchors w*8 + r)
    size_t rowb[8];
#pragma unroll
    for (int r = 0; r < 8; ++r)
        rowb[r] = ((size_t)(s * N_ + n_base + w * 8 + r) * M_ + (size_t)ch * MCH_) * mstride;

    // ds_read addressing: row = msub*32 + t*16 + lrow, chunk = (kc*4+lgrp) ^ (lrow&7)
    const int rb0 = (msub * 32 + lrow) * 256;
    int coff[4];
#pragma unroll
    for (int kc = 0; kc < 4; ++kc) coff[kc] = ((kc * 4 + lgrp) ^ (lrow & 7)) * 16;

    float dmax = NEG_, dsum = 0.f, nsum = 0.f;
    int npos = 0;
    unsigned mvA[8], mvB[8];

    // ---- prologue ----
    {
        // rn stage 0 (async DMA)
        const unsigned char* src = rn_chunk + lane_src_off;
        unsigned char* dst = &smem[0][w * 1024];
#pragma unroll
        for (int j = 0; j < 4; ++j) gll16(src + j * 4096, dst + j * 4096);
        __builtin_amdgcn_sched_barrier(0);
        // mask window 0: load + ballot now
        unsigned char m0[8];
        const size_t e0 = (size_t)lane * mstride;
#pragma unroll
        for (int r = 0; r < 8; ++r) m0[r] = maskb[rowb[r] + e0];
        unsigned long long bl[8];
#pragma unroll
        for (int r = 0; r < 8; ++r) bl[r] = __ballot(m0[r] != 0);
        if (lane == 0) {
#pragma unroll
            for (int r = 0; r < 8; ++r) mbuf[0][w * 8 + r] = bl[r];
        }
        // mask window 1 -> mvA (stays in flight)
        const size_t e1 = (size_t)(64 + lane) * mstride;
#pragma unroll
        for (int r = 0; r < 8; ++r) mvA[r] = maskb[rowb[r] + e1];
        asm volatile("s_waitcnt vmcnt(8)" ::: "memory");   // drain rn DMA only
        __builtin_amdgcn_s_barrier();
    }

// one stage. MVU holds mask window ST+1 (balloted here); MVL gets window ST+2.
#define STAGE(ST, MVU, MVL, DOG, DOM, WAITSTR)                                          \
    {                                                                                   \
        const int nb_ = (ST) & 1;                                                       \
        if (DOG) {                                                                      \
            const unsigned char* src_ = rn_chunk + (size_t)((ST) + 1) * 16384 + lane_src_off; \
            unsigned char* dst_ = &smem[nb_ ^ 1][w * 1024];                             \
            _Pragma("unroll")                                                           \
            for (int j = 0; j < 4; ++j) gll16(src_ + j * 4096, dst_ + j * 4096);        \
        }                                                                               \
        __builtin_amdgcn_sched_barrier(0);                                              \
        if (DOM) {                                                                      \
            const size_t eo_ = (size_t)(((ST) + 2) * 64 + lane) * mstride;              \
            _Pragma("unroll")                                                           \
            for (int r = 0; r < 8; ++r) MVL[r] = maskb[rowb[r] + eo_];                  \
        }                                                                               \
        const unsigned char* base_ = &smem[nb_][0] + rb0;                               \
        f32x4 acc0 = {0.f, 0.f, 0.f, 0.f}, acc1 = {0.f, 0.f, 0.f, 0.f};                 \
        _Pragma("unroll")                                                               \
        for (int kc = 0; kc < 4; ++kc) {                                                \
            acc0 = __builtin_amdgcn_mfma_f32_16x16x32_bf16(                             \
                *reinterpret_cast<const bf16x8*>(base_ + coff[kc]), bfr[kc], acc0, 0, 0, 0); \
            acc1 = __builtin_amdgcn_mfma_f32_16x16x32_bf16(                             \
                *reinterpret_cast<const bf16x8*>(base_ + 4096 + coff[kc]), bfr[kc], acc1, 0, 0, 0); \
        }                                                                               \
        const unsigned long long wmask = mbuf[nb_][nsub * 16 + lrow];                   \
        const unsigned nib0 = (unsigned)(wmask >> (msub * 32 + lgrp * 4)) & 0xFu;       \
        const unsigned nib1 = (unsigned)(wmask >> (msub * 32 + 16 + lgrp * 4)) & 0xFu;  \
        float l0 = acc0[0] * scale2, l1 = acc0[1] * scale2;                             \
        float l2 = acc0[2] * scale2, l3 = acc0[3] * scale2;                             \
        float l4 = acc1[0] * scale2, l5 = acc1[1] * scale2;                             \
        float l6 = acc1[2] * scale2, l7 = acc1[3] * scale2;                             \
        float tmax = fmaxf(fmaxf(fmaxf(l0, l1), fmaxf(l2, l3)),                         \
                           fmaxf(fmaxf(l4, l5), fmaxf(l6, l7)));                        \
        const float nmx = fmaxf(dmax, tmax);                                            \
        const float r_ = exp2f(dmax - nmx);                                             \
        float e0 = exp2f(l0 - nmx), e1 = exp2f(l1 - nmx);                               \
        float e2 = exp2f(l2 - nmx), e3 = exp2f(l3 - nmx);                               \
        float e4 = exp2f(l4 - nmx), e5 = exp2f(l5 - nmx);                               \
        float e6 = exp2f(l6 - nmx), e7 = exp2f(l7 - nmx);                               \
        dsum = dsum * r_ + (((e0 + e1) + (e2 + e3)) + ((e4 + e5) + (e6 + e7)));         \
        float p0 = ((nib0 & 1u) ? e0 : 0.f) + (((nib0 >> 1) & 1u) ? e1 : 0.f);          \
        float p1 = (((nib0 >> 2) & 1u) ? e2 : 0.f) + (((nib0 >> 3) & 1u) ? e3 : 0.f);   \
        float p2 = ((nib1 & 1u) ? e4 : 0.f) + (((nib1 >> 1) & 1u) ? e5 : 0.f);          \
        float p3 = (((nib1 >> 2) & 1u) ? e6 : 0.f) + (((nib1 >> 3) & 1u) ? e7 : 0.f);   \
        nsum = nsum * r_ + ((p0 + p1) + (p2 + p3));                                     \
        npos += __popc(nib0 | (nib1 << 4));                                             \
        dmax = nmx;                                                                     \
        if (DOG) {                                                                      \
            unsigned long long bl_[8];                                                  \
            _Pragma("unroll")                                                           \
            for (int r2 = 0; r2 < 8; ++r2) bl_[r2] = __ballot(MVU[r2] != 0);            \
            if (lane == 0) {                                                            \
                _Pragma("unroll")                                                       \
                for (int r2 = 0; r2 < 8; ++r2) mbuf[nb_ ^ 1][w * 8 + r2] = bl_[r2];     \
            }                                                                           \
        }                                                                               \
        asm volatile(WAITSTR ::: "memory");                                             \
        __builtin_amdgcn_s_barrier();                                                   \
    }

    // main loop: stages 0..27 (st+2 <= 29 always prefetchable)
    for (int st = 0; st < NST_ - 4; st += 2) {
        STAGE(st,     mvA, mvB, true, true, "s_waitcnt vmcnt(8)");
        STAGE(st + 1, mvB, mvA, true, true, "s_waitcnt vmcnt(8)");
    }
    // peeled tail: 28,29 prefetch both; 30 no mask prefetch; 31 nothing
    STAGE(NST_ - 4, mvA, mvB, true,  true,  "s_waitcnt vmcnt(8)");
    STAGE(NST_ - 3, mvB, mvA, true,  true,  "s_waitcnt vmcnt(8)");
    STAGE(NST_ - 2, mvA, mvB, true,  false, "s_waitcnt vmcnt(0)");
    STAGE(NST_ - 1, mvB, mvA, false, false, "s_waitcnt vmcnt(0)");
#undef STAGE

    float npf = (float)npos;
    // merge the 4 lane-groups (same anchor, different m): xor 16, 32
#pragma unroll
    for (int off = 16; off < 64; off <<= 1) {
        float odm = __shfl_xor(dmax, off), ods = __shfl_xor(dsum, off);
        float ons = __shfl_xor(nsum, off), onp = __shfl_xor(npf, off);
        float nm = fmaxf(dmax, odm);
        float ra = exp2f(dmax - nm), rb = exp2f(odm - nm);
        dsum = dsum * ra + ods * rb;
        nsum = nsum * ra + ons * rb;
        npf += onp;
        dmax = nm;
    }

    if (lane < 16) lds4[w][lane] = make_float4(dmax, dsum, nsum, npf);
    __syncthreads();

    // merge msub halves (waves {0,2},{1,3}); write (anchor, chunk) partial
    if (w == 0 && lane < 32) {
        const int wsub = lane >> 4;
        const int ni = lane & 15;
        const float4 A = lds4[wsub][ni];
        const float4 B = lds4[wsub + 2][ni];
        const float nm = fmaxf(A.x, B.x);
        const float ra = exp2f(A.x - nm), rb = exp2f(B.x - nm);
        const float ds = A.y * ra + B.y * rb;
        const float ns = A.z * ra + B.z * rb;
        const float np = A.w + B.w;
        const int ag = s * N_ + n_base + wsub * 16 + ni;
        part4[ag * CH_ + ch] = make_float4(nm, ds, ns, np);
    }
}

// ---------------- Phase 3: merge chunk partials -> per-block (pa,cnt) partial ----------------
__global__ void reduce_kernel(const float4* __restrict__ part4, float2* __restrict__ bpart) {
    const int a = blockIdx.x * 256 + threadIdx.x;   // anchor
    const int w = threadIdx.x >> 6;
    const int lane = threadIdx.x & 63;
    float dm = NEG_, ds = 0.f, ns = 0.f, npf = 0.f;
#pragma unroll
    for (int ch = 0; ch < CH_; ++ch) {
        const float4 p = part4[a * CH_ + ch];
        const float m2 = fmaxf(dm, p.x);
        const float ra = exp2f(dm - m2), rb = exp2f(p.x - m2);
        ds = ds * ra + p.y * rb;
        ns = ns * ra + p.z * rb;
        npf += p.w;
        dm = m2;
    }
    const bool valid = (npf > 0.5f) && (npf < (float)M_ - 0.5f);
    float pa = valid ? LN2_ * (log2f(ds) - log2f(ns)) : 0.f;
    float cv = valid ? 1.f : 0.f;
#pragma unroll
    for (int off = 1; off < 64; off <<= 1) {
        pa += __shfl_xor(pa, off);
        cv += __shfl_xor(cv, off);
    }
    __shared__ float sp[4], sc[4];
    if (lane == 0) { sp[w] = pa; sc[w] = cv; }
    __syncthreads();
    if (threadIdx.x == 0)
        bpart[blockIdx.x] = make_float2(sp[0] + sp[1] + sp[2] + sp[3],
                                        sc[0] + sc[1] + sc[2] + sc[3]);
}

// ---------------- Phase 4: finalize (64 block-partials, 16 per stem) ----------------
__global__ void finalize_kernel(const float2* __restrict__ bpart, float* __restrict__ out) {
    const int t = threadIdx.x;   // 64 threads
    const float2 v = bpart[t];
    float pa = v.x, cv = v.y;
#pragma unroll
    for (int off = 1; off < 16; off <<= 1) {
        pa += __shfl_xor(pa, off);
        cv += __shfl_xor(cv, off);
    }
    const float p0 = __shfl(pa, 0),  c0 = __shfl(cv, 0);
    const float p1 = __shfl(pa, 16), c1 = __shfl(cv, 16);
    const float p2 = __shfl(pa, 32), c2 = __shfl(cv, 32);
    const float p3 = __shfl(pa, 48), c3 = __shfl(cv, 48);
    if (t == 0) {
        float total = 0.f;
        int scnt = 0;
        const float ps[4] = {p0, p1, p2, p3};
        const float cs[4] = {c0, c1, c2, c3};
        for (int s = 0; s < S_; ++s) {
            const float stem = ps[s] / fmaxf(cs[s], 1.f);
            if (cs[s] > 0.f) { total += stem; scnt++; }
        }
        out[0] = total / (float)(scnt > 0 ? scnt : 1);
    }
}

extern "C" void kernel_launch(void* const* d_in, const int* in_sizes, int n_in,
                              void* d_out, int out_size, void* d_ws, size_t ws_size,
                              hipStream_t stream) {
    const float* art = (const float*)d_in[0];
    const float* ref = (const float*)d_in[1];
    const unsigned char* mask = (const unsigned char*)d_in[2];
    const float* lt = (const float*)d_in[3];
    float* out = (float*)d_out;

    char* ws = (char*)d_ws;
    unsigned short* an = (unsigned short*)ws;                       // 4 MB
    unsigned short* rn = (unsigned short*)(ws + (size_t)4194304);   // 4 MB
    float4* part4 = (float4*)(ws + (size_t)8388608);                // 512 KB
    float2* bpart = (float2*)(ws + (size_t)9437184);                // 512 B

    nrm_rows_kernel<<<(S_ * (N_ + M_)) / 8, 256, 0, stream>>>(art, ref, an, rn);
    infonce_main_kernel<<<S_ * (N_ / 32) * CH_, 256, 0, stream>>>(an, rn, mask, lt, part4);
    reduce_kernel<<<(S_ * N_) / 256, 256, 0, stream>>>(part4, bpart);
    finalize_kernel<<<1, 64, 0, stream>>>(bpart, out);
}

// Round 9
// 400.274 us; speedup vs baseline: 1.0299x; 1.0299x over previous
//
#include <hip/hip_runtime.h>
#include <hip/hip_bf16.h>
#include <math.h>

#define S_ 4
#define N_ 4096
#define M_ 4096
#define D_ 128
#define NEG_ (-1e30f)
#define CH_ 2              // m-chunks per stem
#define MCH_ (M_ / CH_)    // 2048 m per chunk
#define NST_ (MCH_ / 64)   // 32 stages of 64 m
#define NGRP_ (NST_ / 4)   // 8 mask groups of 256 m
#define LN2_ 0.69314718055994531f
#define LOG2E_ 1.44269504088896340f

typedef __bf16 bf16x8 __attribute__((ext_vector_type(8)));
typedef float f32x4 __attribute__((ext_vector_type(4)));

// async global->LDS, 16B per lane (dest = wave-uniform base + lane*16)
__device__ __forceinline__ void gll16(const void* g, void* l) {
    __builtin_amdgcn_global_load_lds(
        (const __attribute__((address_space(1))) unsigned int*)g,
        (__attribute__((address_space(3))) unsigned int*)l, 16, 0, 0);
}

// RNE float -> bf16 bits
__device__ __forceinline__ unsigned short f2bf(float f) {
    unsigned u = __float_as_uint(f);
    unsigned r = (u + 0x7FFFu + ((u >> 16) & 1u)) >> 16;
    return (unsigned short)r;
}

// ---------------- Phase 1: L2-normalize art AND ref rows, write bf16 ----------------
__global__ void nrm_rows_kernel(const float* __restrict__ art, const float* __restrict__ ref,
                                unsigned short* __restrict__ an, unsigned short* __restrict__ rn) {
    const int w = threadIdx.x >> 6;
    const int lane = threadIdx.x & 63;
    const int half = lane >> 5;
    const int li = lane & 31;
    const int row = blockIdx.x * 8 + w * 2 + half;   // 0 .. S_*(N_+M_)-1
    const bool is_art = row < S_ * N_;
    const float* src = is_art ? (art + (size_t)row * D_)
                              : (ref + (size_t)(row - S_ * N_) * D_);
    unsigned short* dst = is_art ? (an + (size_t)row * D_)
                                 : (rn + (size_t)(row - S_ * N_) * D_);
    const float4 v = *reinterpret_cast<const float4*>(src + li * 4);
    float ss = v.x * v.x + v.y * v.y + v.z * v.z + v.w * v.w;
#pragma unroll
    for (int off = 1; off < 32; off <<= 1) ss += __shfl_xor(ss, off);
    const float scale = 1.0f / fmaxf(sqrtf(ss), 1e-12f);
    uint2 pack;
    pack.x = (unsigned)f2bf(v.x * scale) | ((unsigned)f2bf(v.y * scale) << 16);
    pack.y = (unsigned)f2bf(v.z * scale) | ((unsigned)f2bf(v.w * scale) << 16);
    *reinterpret_cast<uint2*>(dst + li * 4) = pack;
}

// mask group load: per row r, lane loads 4 consecutive elements (g*256 + 4*lane .. +3)
template <int ESZ>
__device__ __forceinline__ void mload(int4* mq, const unsigned char* __restrict__ maskb,
                                      const size_t* rowb, int g, int lane) {
#pragma unroll
    for (int r = 0; r < 8; ++r) {
        const unsigned char* p = maskb + rowb[r] + (size_t)((g * 256 + 4 * lane) * ESZ);
        if (ESZ == 4) mq[r] = *reinterpret_cast<const int4*>(p);
        else          mq[r].x = *reinterpret_cast<const int*>(p);
    }
}

template <int ESZ>
__device__ __forceinline__ unsigned nib_of(const int4 q) {
    if (ESZ == 4)
        return (unsigned)((q.x != 0) | ((q.y != 0) << 1) | ((q.z != 0) << 2) | ((q.w != 0) << 3));
    const unsigned b = (unsigned)q.x;   // 4 bool bytes
    return (((b & 0xFFu) != 0) ? 1u : 0u) | (((b >> 8) & 0xFFu) ? 2u : 0u)
         | (((b >> 16) & 0xFFu) ? 4u : 0u) | ((b >> 24) ? 8u : 0u);
}

// ---------------- Phase 2 body (templated on mask element size) ----------------
template <int ESZ>
__device__ __forceinline__ void run_main(
    const unsigned short* __restrict__ an, const unsigned short* __restrict__ rn,
    const unsigned char* __restrict__ maskb, float scale2, float4* __restrict__ part4,
    int s, int ch, int n_base,
    unsigned char (&smem)[2][64 * 256], unsigned char (&mnib)[2][32][68],
    float4 (&lds4)[4][16]) {

    const int tid = threadIdx.x;
    const int w = tid >> 6;
    const int lane = tid & 63;
    const int nsub = w & 1;
    const int msub = w >> 1;
    const int n16 = n_base + nsub * 16;
    const int lrow = lane & 15;        // anchor col within 16-group
    const int lgrp = lane >> 4;        // k-group / m-row group

    // anchor fragments resident in registers
    bf16x8 bfr[4];
    const unsigned short* abase = an + ((size_t)(s * N_ + n16 + lrow)) * D_ + lgrp * 8;
#pragma unroll
    for (int kc = 0; kc < 4; ++kc)
        bfr[kc] = *reinterpret_cast<const bf16x8*>(abase + kc * 32);

    // rn staging: thread covers row srow (+j*16), 16B chunk (lane&15), source XOR-swizzled
    const int srow = w * 4 + (lane >> 4);
    const int schunk = (lane & 15) ^ (srow & 7);
    const int lane_src_off = srow * 256 + schunk * 16;
    const unsigned char* rn_chunk =
        (const unsigned char*)(rn + ((size_t)(s * M_ + ch * MCH_)) * D_);

    // mask row byte-bases for this wave's 8 rows (block anchors w*8 + r)
    size_t rowb[8];
#pragma unroll
    for (int r = 0; r < 8; ++r)
        rowb[r] = ((size_t)(s * N_ + n_base + w * 8 + r) * M_ + (size_t)ch * MCH_) * ESZ;

    // ds_read addressing: row = msub*32 + t*16 + lrow, chunk = (kc*4+lgrp) ^ (lrow&7)
    const int rb0 = (msub * 32 + lrow) * 256;
    int coff[4];
#pragma unroll
    for (int kc = 0; kc < 4; ++kc) coff[kc] = ((kc * 4 + lgrp) ^ (lrow & 7)) * 16;

    float dmax = NEG_, dsum = 0.f, nsum = 0.f;
    int npos = 0;
    int4 mq[8];

    // ---- prologue: rn stage 0, mask group 0 (convert now) + group 1 (in flight) ----
    {
        const unsigned char* src = rn_chunk + lane_src_off;
        unsigned char* dst = &smem[0][w * 1024];
#pragma unroll
        for (int j = 0; j < 4; ++j) gll16(src + j * 4096, dst + j * 4096);
        mload<ESZ>(mq, maskb, rowb, 0, lane);
#pragma unroll
        for (int r = 0; r < 8; ++r)
            mnib[0][w * 8 + r][lane] = (unsigned char)nib_of<ESZ>(mq[r]);
        mload<ESZ>(mq, maskb, rowb, 1, lane);
        __syncthreads();
    }

    for (int g = 0; g < NGRP_; ++g) {
#pragma unroll
        for (int j = 0; j < 4; ++j) {
            const int st = g * 4 + j;
            const int nb = j & 1;                      // (4g+j)&1 == j&1
            // rn prefetch for st+1
            if (j < 3 || g < NGRP_ - 1) {
                const unsigned char* src_ = rn_chunk + (size_t)(st + 1) * 16384 + lane_src_off;
                unsigned char* dst_ = &smem[nb ^ 1][w * 1024];
#pragma unroll
                for (int jj = 0; jj < 4; ++jj) gll16(src_ + jj * 4096, dst_ + jj * 4096);
            }
            // mask maintenance once per group (j==3): convert mq (group g+1) -> mnib,
            // then issue group g+2 loads (deep prefetch, arrives 4 stages later)
            if (j == 3 && g < NGRP_ - 1) {
#pragma unroll
                for (int r = 0; r < 8; ++r)
                    mnib[(g + 1) & 1][w * 8 + r][lane] = (unsigned char)nib_of<ESZ>(mq[r]);
                if (g < NGRP_ - 2) mload<ESZ>(mq, maskb, rowb, g + 2, lane);
            }
            // ---- 2 MFMA tiles from LDS ----
            const unsigned char* base_ = &smem[nb][0] + rb0;
            f32x4 acc0 = {0.f, 0.f, 0.f, 0.f}, acc1 = {0.f, 0.f, 0.f, 0.f};
#pragma unroll
            for (int kc = 0; kc < 4; ++kc) {
                acc0 = __builtin_amdgcn_mfma_f32_16x16x32_bf16(
                    *reinterpret_cast<const bf16x8*>(base_ + coff[kc]), bfr[kc], acc0, 0, 0, 0);
                acc1 = __builtin_amdgcn_mfma_f32_16x16x32_bf16(
                    *reinterpret_cast<const bf16x8*>(base_ + 4096 + coff[kc]), bfr[kc], acc1, 0, 0, 0);
            }
            // ---- nibble reads (conflict-free: row stride 68, 17 coprime 32) ----
            const int row = nsub * 16 + lrow;
            const int nidx = j * 16 + msub * 8 + lgrp;
            const unsigned nib0 = mnib[g & 1][row][nidx];
            const unsigned nib1 = mnib[g & 1][row][nidx + 4];
            // ---- epilogue: 8 logits (2 tiles x 4 m) ----
            float l0 = acc0[0] * scale2, l1 = acc0[1] * scale2;
            float l2 = acc0[2] * scale2, l3 = acc0[3] * scale2;
            float l4 = acc1[0] * scale2, l5 = acc1[1] * scale2;
            float l6 = acc1[2] * scale2, l7 = acc1[3] * scale2;
            float tmax = fmaxf(fmaxf(fmaxf(l0, l1), fmaxf(l2, l3)),
                               fmaxf(fmaxf(l4, l5), fmaxf(l6, l7)));
            const float nmx = fmaxf(dmax, tmax);
            const float r_ = exp2f(dmax - nmx);
            float e0 = exp2f(l0 - nmx), e1 = exp2f(l1 - nmx);
            float e2 = exp2f(l2 - nmx), e3 = exp2f(l3 - nmx);
            float e4 = exp2f(l4 - nmx), e5 = exp2f(l5 - nmx);
            float e6 = exp2f(l6 - nmx), e7 = exp2f(l7 - nmx);
            dsum = dsum * r_ + (((e0 + e1) + (e2 + e3)) + ((e4 + e5) + (e6 + e7)));
            float p0 = ((nib0 & 1u) ? e0 : 0.f) + (((nib0 >> 1) & 1u) ? e1 : 0.f);
            float p1 = (((nib0 >> 2) & 1u) ? e2 : 0.f) + (((nib0 >> 3) & 1u) ? e3 : 0.f);
            float p2 = ((nib1 & 1u) ? e4 : 0.f) + (((nib1 >> 1) & 1u) ? e5 : 0.f);
            float p3 = (((nib1 >> 2) & 1u) ? e6 : 0.f) + (((nib1 >> 3) & 1u) ? e7 : 0.f);
            nsum = nsum * r_ + ((p0 + p1) + (p2 + p3));
            npos += __popc(nib0 | (nib1 << 4));
            dmax = nmx;
            __syncthreads();
        }
    }

    float npf = (float)npos;
    // merge the 4 lane-groups (same anchor, different m): xor 16, 32
#pragma unroll
    for (int off = 16; off < 64; off <<= 1) {
        float odm = __shfl_xor(dmax, off), ods = __shfl_xor(dsum, off);
        float ons = __shfl_xor(nsum, off), onp = __shfl_xor(npf, off);
        float nm = fmaxf(dmax, odm);
        float ra = exp2f(dmax - nm), rb = exp2f(odm - nm);
        dsum = dsum * ra + ods * rb;
        nsum = nsum * ra + ons * rb;
        npf += onp;
        dmax = nm;
    }

    if (lane < 16) lds4[w][lane] = make_float4(dmax, dsum, nsum, npf);
    __syncthreads();

    // merge msub halves (waves {0,2},{1,3}); write (anchor, chunk) partial
    if (w == 0 && lane < 32) {
        const int wsub = lane >> 4;
        const int ni = lane & 15;
        const float4 A = lds4[wsub][ni];
        const float4 B = lds4[wsub + 2][ni];
        const float nm = fmaxf(A.x, B.x);
        const float ra = exp2f(A.x - nm), rb = exp2f(B.x - nm);
        const float ds = A.y * ra + B.y * rb;
        const float ns = A.z * ra + B.z * rb;
        const float np = A.w + B.w;
        const int ag = s * N_ + n_base + wsub * 16 + ni;
        part4[ag * CH_ + ch] = make_float4(nm, ds, ns, np);
    }
}

// ---------------- Phase 2: dispatcher kernel ----------------
__global__ __launch_bounds__(256, 4) void infonce_main_kernel(
    const unsigned short* __restrict__ an, const unsigned short* __restrict__ rn,
    const unsigned char* __restrict__ maskb, const float* __restrict__ logtemp,
    float4* __restrict__ part4) {

    const int bid = blockIdx.x;
    const int swz = (bid & 7) * 128 + (bid >> 3);   // 1024 % 8 == 0 -> bijective
    const int ch = swz >> 9;
    const int s = (swz >> 7) & 3;
    const int n_base = (swz & 127) * 32;
    const float scale2 = __expf(-logtemp[0]) * LOG2E_;   // 1/(temp*ln2)

    // mask dtype detection over 1 KB: byte-packed bools seen as u32 show values > 1
    const unsigned* mu = (const unsigned*)maskb;
    unsigned pr = 0;
#pragma unroll
    for (int i = 0; i < 4; ++i) pr |= (mu[i * 64 + (threadIdx.x & 63)] > 1u) ? 1u : 0u;
    const bool byte_mode = (__ballot(pr != 0) != 0ull);

    __shared__ unsigned char smem[2][64 * 256];     // 2 x 16 KB rn stage buffers
    __shared__ unsigned char mnib[2][32][68];       // nibble table, padded stride
    __shared__ float4 lds4[4][16];

    if (byte_mode)
        run_main<1>(an, rn, maskb, scale2, part4, s, ch, n_base, smem, mnib, lds4);
    else
        run_main<4>(an, rn, maskb, scale2, part4, s, ch, n_base, smem, mnib, lds4);
}

// ---------------- Phase 3: merge chunk partials -> per-block (pa,cnt) partial ----------------
__global__ void reduce_kernel(const float4* __restrict__ part4, float2* __restrict__ bpart) {
    const int a = blockIdx.x * 256 + threadIdx.x;   // anchor
    const int w = threadIdx.x >> 6;
    const int lane = threadIdx.x & 63;
    float dm = NEG_, ds = 0.f, ns = 0.f, npf = 0.f;
#pragma unroll
    for (int ch = 0; ch < CH_; ++ch) {
        const float4 p = part4[a * CH_ + ch];
        const float m2 = fmaxf(dm, p.x);
        const float ra = exp2f(dm - m2), rb = exp2f(p.x - m2);
        ds = ds * ra + p.y * rb;
        ns = ns * ra + p.z * rb;
        npf += p.w;
        dm = m2;
    }
    const bool valid = (npf > 0.5f) && (npf < (float)M_ - 0.5f);
    float pa = valid ? LN2_ * (log2f(ds) - log2f(ns)) : 0.f;
    float cv = valid ? 1.f : 0.f;
#pragma unroll
    for (int off = 1; off < 64; off <<= 1) {
        pa += __shfl_xor(pa, off);
        cv += __shfl_xor(cv, off);
    }
    __shared__ float sp[4], sc[4];
    if (lane == 0) { sp[w] = pa; sc[w] = cv; }
    __syncthreads();
    if (threadIdx.x == 0)
        bpart[blockIdx.x] = make_float2(sp[0] + sp[1] + sp[2] + sp[3],
                                        sc[0] + sc[1] + sc[2] + sc[3]);
}

// ---------------- Phase 4: finalize (64 block-partials, 16 per stem) ----------------
__global__ void finalize_kernel(const float2* __restrict__ bpart, float* __restrict__ out) {
    const int t = threadIdx.x;   // 64 threads
    const float2 v = bpart[t];
    float pa = v.x, cv = v.y;
#pragma unroll
    for (int off = 1; off < 16; off <<= 1) {
        pa += __shfl_xor(pa, off);
        cv += __shfl_xor(cv, off);
    }
    const float p0 = __shfl(pa, 0),  c0 = __shfl(cv, 0);
    const float p1 = __shfl(pa, 16), c1 = __shfl(cv, 16);
    const float p2 = __shfl(pa, 32), c2 = __shfl(cv, 32);
    const float p3 = __shfl(pa, 48), c3 = __shfl(cv, 48);
    if (t == 0) {
        float total = 0.f;
        int scnt = 0;
        const float ps[4] = {p0, p1, p2, p3};
        const float cs[4] = {c0, c1, c2, c3};
        for (int s = 0; s < S_; ++s) {
            const float stem = ps[s] / fmaxf(cs[s], 1.f);
            if (cs[s] > 0.f) { total += stem; scnt++; }
        }
        out[0] = total / (float)(scnt > 0 ? scnt : 1);
    }
}

extern "C" void kernel_launch(void* const* d_in, const int* in_sizes, int n_in,
                              void* d_out, int out_size, void* d_ws, size_t ws_size,
                              hipStream_t stream) {
    const float* art = (const float*)d_in[0];
    const float* ref = (const float*)d_in[1];
    const unsigned char* mask = (const unsigned char*)d_in[2];
    const float* lt = (const float*)d_in[3];
    float* out = (float*)d_out;

    char* ws = (char*)d_ws;
    unsigned short* an = (unsigned short*)ws;                       // 4 MB
    unsigned short* rn = (unsigned short*)(ws + (size_t)4194304);   // 4 MB
    float4* part4 = (float4*)(ws + (size_t)8388608);                // 512 KB
    float2* bpart = (float2*)(ws + (size_t)9437184);                // 512 B

    nrm_rows_kernel<<<(S_ * (N_ + M_)) / 8, 256, 0, stream>>>(art, ref, an, rn);
    infonce_main_kernel<<<S_ * (N_ / 32) * CH_, 256, 0, stream>>>(an, rn, mask, lt, part4);
    reduce_kernel<<<(S_ * N_) / 256, 256, 0, stream>>>(part4, bpart);
    finalize_kernel<<<1, 64, 0, stream>>>(bpart, out);
}